// Round 3
// baseline (568.542 us; speedup 1.0000x reference)
//
#include <hip/hip_runtime.h>

// Problem constants (B=2,S=2048,D=1024,E=8,DFF=2048,top_k=2)
#define T_TOK 4096
#define DIM   1024
#define DFF   2048
#define NE    8
#define NR    7    // routed experts (E-1)
#define MAXNB 71   // max routed row-blocks: 8192/128 + 7
#define NY    (32 + MAXNB)   // unified sched entries: 32 e0 + routed
#define G_BUF 20480          // ushorts per LDS buffer (40960 B): A 4096 | B 16384

typedef __bf16 bf16x8 __attribute__((ext_vector_type(8)));
typedef float  floatx4 __attribute__((ext_vector_type(4)));

__device__ __forceinline__ unsigned short f32_bf16(float f) {
  union { float f; unsigned int u; } v; v.f = f;
  unsigned int u = v.u;
  unsigned int r = (u + 0x7FFFu + ((u >> 16) & 1u)) >> 16;  // RNE
  return (unsigned short)r;
}

typedef __attribute__((address_space(3))) void lds_void_t;
typedef const __attribute__((address_space(1))) void g_void_t;

__device__ __forceinline__ void gld16(const void* g, void* l) {
  // async global->LDS, 16B/lane; LDS dest = wave-uniform base + lane*16 (m104)
  __builtin_amdgcn_global_load_lds((g_void_t*)g, (lds_void_t*)l, 16, 0, 0);
}

// ---------------- x fp32 -> bf16 ----------------
__global__ __launch_bounds__(256) void cvt_x_kernel(const float4* __restrict__ in,
                                                    ushort4* __restrict__ out) {
  int i = blockIdx.x * 256 + threadIdx.x;
  float4 v = in[i];
  ushort4 o;
  o.x = f32_bf16(v.x); o.y = f32_bf16(v.y);
  o.z = f32_bf16(v.z); o.w = f32_bf16(v.w);
  out[i] = o;
}

// ---------------- router: top-2 -> routed seat lists + per-token records ----------------
__global__ __launch_bounds__(256) void router_kernel(const float* __restrict__ x,
                                                     const float* __restrict__ rw,
                                                     const float* __restrict__ rb,
                                                     int* __restrict__ idxR,
                                                     float* __restrict__ wslR,
                                                     int* __restrict__ cnt,
                                                     int4* __restrict__ tokE,
                                                     float2* __restrict__ tokW) {
  const int lane = threadIdx.x & 63;
  const int t = blockIdx.x * 4 + (threadIdx.x >> 6);  // one wave per token
  const float* xr = x + (size_t)t * DIM;
  float acc[NR];
#pragma unroll
  for (int e = 0; e < NR; e++) acc[e] = 0.f;
  for (int d = lane; d < DIM; d += 64) {
    float xv = xr[d];
#pragma unroll
    for (int e = 0; e < NR; e++) acc[e] += xv * rw[d * NR + e];
  }
#pragma unroll
  for (int off = 32; off > 0; off >>= 1) {
#pragma unroll
    for (int e = 0; e < NR; e++) acc[e] += __shfl_xor(acc[e], off, 64);
  }
  if (lane == 0) {
    float lg[NR];
    float m = -1e30f;
#pragma unroll
    for (int e = 0; e < NR; e++) { lg[e] = acc[e] + rb[e]; m = fmaxf(m, lg[e]); }
    float p[NR], s = 0.f;
#pragma unroll
    for (int e = 0; e < NR; e++) { p[e] = expf(lg[e] - m); s += p[e]; }
#pragma unroll
    for (int e = 0; e < NR; e++) p[e] /= s;
    int i1 = 0;
#pragma unroll
    for (int e = 1; e < NR; e++) if (p[e] > p[i1]) i1 = e;   // ties -> lowest index (jax)
    int i2 = (i1 == 0) ? 1 : 0;
#pragma unroll
    for (int e = 0; e < NR; e++) if (e != i1 && p[e] > p[i2]) i2 = e;
    float w1 = p[i1], w2 = p[i2], sw = w1 + w2;
    float w1n = w1 / sw, w2n = w2 / sw;
    int s1 = atomicAdd(&cnt[i1], 1);
    idxR[i1 * 4096 + s1] = t; wslR[i1 * 4096 + s1] = w1n;
    int s2 = atomicAdd(&cnt[i2], 1);
    idxR[i2 * 4096 + s2] = t; wslR[i2 * 4096 + s2] = w2n;
    int4 te; te.x = i1; te.y = s1; te.z = i2; te.w = s2;
    tokE[t] = te;
    float2 tw; tw.x = w1n; tw.y = w2n;
    tokW[t] = tw;
  }
}

// ---------------- schedule tables ----------------
__global__ __launch_bounds__(256) void sched_kernel(const int* __restrict__ cnt,
                                                    int* __restrict__ idxR,
                                                    float* __restrict__ wslR,
                                                    int4* __restrict__ schedAll,
                                                    int4* __restrict__ schedP,
                                                    int* __restrict__ prefOut,
                                                    int rsb) {
  __shared__ int nb[NR], pref[NR];
  if (threadIdx.x == 0) {
    int p = 0;
    for (int e = 0; e < NR; e++) { int c = cnt[e]; int n = (c + 127) >> 7; nb[e] = n; pref[e] = p; p += n; }
  }
  __syncthreads();
  if (threadIdx.x < NR) prefOut[threadIdx.x] = pref[threadIdx.x];
  for (int e = 0; e < NR; e++) {
    int c = cnt[e], top = nb[e] * 128;
    for (int i = c + (int)threadIdx.x; i < top; i += 256) {
      idxR[e * 4096 + i] = 0; wslR[e * 4096 + i] = 0.f;
    }
  }
  const int NBtot = pref[NR - 1] + nb[NR - 1];
  for (int y = threadIdx.x; y < 32; y += 256) {
    int4 ent; ent.x = 0; ent.y = -1; ent.z = y * 128; ent.w = 0;
    schedAll[y] = ent;
  }
  for (int y = threadIdx.x; y < MAXNB; y += 256) {
    int4 ent; ent.x = -1; ent.y = 0; ent.z = 0; ent.w = 0;
    if (y < NBtot) {
#pragma unroll
      for (int e = 0; e < NR; e++)
        if (y >= pref[e] && y < pref[e] + nb[e]) {
          int rb2 = y - pref[e];
          ent.x = e + 1; ent.y = e * 4096 + rb2 * 128; ent.z = rsb + y * 128;
        }
    }
    schedAll[32 + y] = ent;
  }
  for (int i = threadIdx.x; i < NR * 32; i += 256) {
    int e = i >> 5, rb2 = i & 31;
    int4 ent; ent.w = 0;
    if (rb2 < nb[e]) { ent.x = e + 1; ent.y = e * 4096 + rb2 * 128; ent.z = rb2 * 128; }
    else             { ent.x = -1; ent.y = 0; ent.z = 0; }
    schedP[i] = ent;
  }
}

// ---------------- weight transpose + fp32->bf16 (64x64 tiles, 8B writes) ----------------
__global__ __launch_bounds__(256) void transpose_cvt_kernel(
    const float* __restrict__ wg, const float* __restrict__ wu, const float* __restrict__ wd,
    unsigned short* __restrict__ wgt, unsigned short* __restrict__ wut,
    unsigned short* __restrict__ wdt) {
  __shared__ float tile[64][65];
  const int z = blockIdx.z;
  const float* src; unsigned short* dst; int R, C;
  if (z < 8)       { src = wg + (size_t)z * DIM * DFF;        dst = wgt + (size_t)z * DIM * DFF;        R = DIM; C = DFF; }
  else if (z < 16) { src = wu + (size_t)(z - 8) * DIM * DFF;  dst = wut + (size_t)(z - 8) * DIM * DFF;  R = DIM; C = DFF; }
  else             { src = wd + (size_t)(z - 16) * DFF * DIM; dst = wdt + (size_t)(z - 16) * DFF * DIM; R = DFF; C = DIM; }
  const int c0 = blockIdx.x * 64, r0 = blockIdx.y * 64;
  if (c0 >= C || r0 >= R) return;
  const int tx = threadIdx.x & 63, ty = threadIdx.x >> 6;   // ty 0..3
#pragma unroll
  for (int j = ty; j < 64; j += 4)
    tile[j][tx] = src[(size_t)(r0 + j) * C + c0 + tx];
  __syncthreads();
  const int r2 = (threadIdx.x & 15) * 4, jj = threadIdx.x >> 4;  // jj 0..15
#pragma unroll
  for (int j = jj; j < 64; j += 16) {
    unsigned int lo = (unsigned int)f32_bf16(tile[r2 + 0][j]) | ((unsigned int)f32_bf16(tile[r2 + 1][j]) << 16);
    unsigned int hi = (unsigned int)f32_bf16(tile[r2 + 2][j]) | ((unsigned int)f32_bf16(tile[r2 + 3][j]) << 16);
    uint2 o; o.x = lo; o.y = hi;
    *(uint2*)(dst + (size_t)(c0 + j) * R + r0 + r2) = o;
  }
}

// ============ GEMM1: BM=128, BN=256 per matrix (g+u), BK=32, wave tile 64x128 ============
// LDS buffer (40KB): A[128 rows x 32] | Bg[256 x 32] | Bu[256 x 32], rows paired into
// 128B physical rows with chunk swizzle c ^= (pr&7) (bank-conflict-free b128 reads).
// 3 buffers, 1 barrier/K-tile, counted vmcnt(5) (5 loads/tile, lookahead 2).
__global__ __launch_bounds__(512, 2) void gemm1_kernel(
    const unsigned short* __restrict__ xb, const unsigned short* __restrict__ wgt,
    const unsigned short* __restrict__ wut, const int* __restrict__ idxR,
    const int4* __restrict__ sched, unsigned short* __restrict__ h, int gy) {
  // bijective XCD-aware swizzle (m204); bx slowest -> each XCD owns one 256-col weight slice
  const int nblk = gridDim.x;
  int bid = blockIdx.x;
  { int q = nblk >> 3, r = nblk & 7, xc = bid & 7, p = bid >> 3;
    bid = (xc < r ? xc * (q + 1) : r * (q + 1) + (xc - r) * q) + p; }
  const int bx = bid / gy, by = bid - bx * gy;
  const int4 ent = sched[by];
  if (ent.x < 0) return;
  __shared__ unsigned short smem[3 * G_BUF];
  const int tid = threadIdx.x, lane = tid & 63, wid = tid >> 6;
  const int n0 = bx * 256;
  const int wm = (wid >> 2) * 64;     // 0 / 64
  const int wn = (wid & 3) * 64;      // 0..192
  const int fr = lane & 15, kq = lane >> 4;   // kq = k-chunk 0..3 (8 elems each)
  // per-lane swizzled fragment offset (ushorts): paired-row layout + XOR chunk swizzle
  const int pl = (fr >> 1) * 64 + (((((fr & 1) << 2) | kq) ^ (fr >> 1)) << 3);
  int offA[4], offG[4], offU[4];
#pragma unroll
  for (int mi = 0; mi < 4; mi++) offA[mi] = (wm + mi * 16) * 32 + pl;
#pragma unroll
  for (int ni = 0; ni < 4; ni++) {
    offG[ni] = 4096 + (wn + ni * 16) * 32 + pl;
    offU[ni] = 12288 + (wn + ni * 16) * 32 + pl;
  }
  // staging decomposition: thread t -> LDS chunk t (pr=t>>3, c=t&7); source chunk cs=c^(pr&7)
  const int prA = tid >> 3;
  const int csA = (tid & 7) ^ (prA & 7);
  const int rowS = 2 * prA + (csA >> 2);      // 0..127
  const int colS = (csA & 3) * 8;             // elem offset within the 32-elem K-tile
  int tokA;
  if (ent.y < 0) tokA = ent.z + rowS;
  else           tokA = idxR[ent.y + rowS];
  const unsigned short* wgt_e = wgt + (size_t)ent.x * DIM * DFF;
  const unsigned short* wut_e = wut + (size_t)ent.x * DIM * DFF;
  const unsigned short* gA  = xb + (size_t)tokA * DIM + colS;
  const unsigned short* gG0 = wgt_e + (size_t)(n0 + rowS) * DIM + colS;
  const unsigned short* gG1 = gG0 + (size_t)128 * DIM;
  const unsigned short* gU0 = wut_e + (size_t)(n0 + rowS) * DIM + colS;
  const unsigned short* gU1 = gU0 + (size_t)128 * DIM;
  floatx4 accg[4][4], accu[4][4];
  const floatx4 z4 = {0.f, 0.f, 0.f, 0.f};
#pragma unroll
  for (int i = 0; i < 4; i++)
#pragma unroll
    for (int j = 0; j < 4; j++) { accg[i][j] = z4; accu[i][j] = z4; }
  // prologue: stage tiles 0,1 (5 loads each: A,G0,G1,U0,U1)
  {
    unsigned short* d = smem + tid * 8;
    gld16(gA, d); gld16(gG0, d + 4096); gld16(gG1, d + 8192);
    gld16(gU0, d + 12288); gld16(gU1, d + 16384);
    unsigned short* e = smem + G_BUF + tid * 8;
    gld16(gA + 32, e); gld16(gG0 + 32, e + 4096); gld16(gG1 + 32, e + 8192);
    gld16(gU0 + 32, e + 12288); gld16(gU1 + 32, e + 16384);
  }
  asm volatile("s_waitcnt vmcnt(5)" ::: "memory");
  __builtin_amdgcn_s_barrier();
  int b = 0;
  for (int k = 0; k < 32; ++k) {
    const unsigned short* Bb = smem + b * G_BUF;
    int b2 = b + 2; if (b2 >= 3) b2 -= 3;
    unsigned short* db2 = smem + b2 * G_BUF + tid * 8;
    if (k < 30) {
      const int kt = (k + 2) * 32;
      gld16(gA + kt, db2); gld16(gG0 + kt, db2 + 4096); gld16(gG1 + kt, db2 + 8192);
      gld16(gU0 + kt, db2 + 12288); gld16(gU1 + kt, db2 + 16384);
    }
    __builtin_amdgcn_sched_barrier(0);  // stage issues stay ahead of reads
    bf16x8 a[4], g[4], u[4];
#pragma unroll
    for (int mi = 0; mi < 4; mi++) a[mi] = *(const bf16x8*)(Bb + offA[mi]);
#pragma unroll
    for (int ni = 0; ni < 4; ni++) {
      g[ni] = *(const bf16x8*)(Bb + offG[ni]);
      u[ni] = *(const bf16x8*)(Bb + offU[ni]);
    }
    __builtin_amdgcn_s_setprio(1);
#pragma unroll
    for (int mi = 0; mi < 4; mi++)
#pragma unroll
      for (int ni = 0; ni < 4; ni++)
        accg[mi][ni] = __builtin_amdgcn_mfma_f32_16x16x32_bf16(a[mi], g[ni], accg[mi][ni], 0, 0, 0);
#pragma unroll
    for (int mi = 0; mi < 4; mi++)
#pragma unroll
      for (int ni = 0; ni < 4; ni++)
        accu[mi][ni] = __builtin_amdgcn_mfma_f32_16x16x32_bf16(a[mi], u[ni], accu[mi][ni], 0, 0, 0);
    __builtin_amdgcn_s_setprio(0);
    __builtin_amdgcn_sched_barrier(0);  // rule #18: nothing sinks past the barrier
    if (k < 30)       asm volatile("s_waitcnt vmcnt(5)" ::: "memory");
    else if (k == 30) asm volatile("s_waitcnt vmcnt(0)" ::: "memory");
    __builtin_amdgcn_s_barrier();
    b++; if (b == 3) b = 0;
  }
  // epilogue: fused silu(g)*u -> bf16 h
  const int rb = kq * 4;
#pragma unroll
  for (int mi = 0; mi < 4; mi++)
#pragma unroll
    for (int ni = 0; ni < 4; ni++)
#pragma unroll
      for (int r = 0; r < 4; r++) {
        int row = ent.z + wm + mi * 16 + rb + r;
        int col = n0 + wn + ni * 16 + fr;
        float gv = accg[mi][ni][r], uv = accu[mi][ni][r];
        float hv = (gv / (1.f + __expf(-gv))) * uv;
        h[(size_t)row * DFF + col] = f32_bf16(hv);
      }
}

// ============ GEMM2: BM=128, BN=512, BK=32, wave tile 64x128 ============
__global__ __launch_bounds__(512, 2) void gemm2_kernel(
    const unsigned short* __restrict__ hsrc, const unsigned short* __restrict__ wdt,
    const int4* __restrict__ sched, float* __restrict__ y, int gy) {
  const int nblk = gridDim.x;
  int bid = blockIdx.x;
  { int q = nblk >> 3, r = nblk & 7, xc = bid & 7, p = bid >> 3;
    bid = (xc < r ? xc * (q + 1) : r * (q + 1) + (xc - r) * q) + p; }
  const int bx = bid / gy, by = bid - bx * gy;
  const int4 ent = sched[by];
  if (ent.x < 0) return;
  __shared__ unsigned short smem[3 * G_BUF];
  const int tid = threadIdx.x, lane = tid & 63, wid = tid >> 6;
  const int n0 = bx * 512;
  const int wm = (wid >> 2) * 64;
  const int wn = (wid & 3) * 128;     // 0..384
  const int fr = lane & 15, kq = lane >> 4;
  const int pl = (fr >> 1) * 64 + (((((fr & 1) << 2) | kq) ^ (fr >> 1)) << 3);
  int offA[4], offB[8];
#pragma unroll
  for (int mi = 0; mi < 4; mi++) offA[mi] = (wm + mi * 16) * 32 + pl;
#pragma unroll
  for (int ni = 0; ni < 8; ni++) offB[ni] = 4096 + (wn + ni * 16) * 32 + pl;
  const int prA = tid >> 3;
  const int csA = (tid & 7) ^ (prA & 7);
  const int rowS = 2 * prA + (csA >> 2);
  const int colS = (csA & 3) * 8;
  const unsigned short* wdt_e = wdt + (size_t)ent.x * DFF * DIM;
  const unsigned short* gA  = hsrc + (size_t)(ent.z + rowS) * DFF + colS;
  const unsigned short* gB0 = wdt_e + (size_t)(n0 + rowS) * DFF + colS;
  const unsigned short* gB1 = gB0 + (size_t)128 * DFF;
  const unsigned short* gB2 = gB0 + (size_t)256 * DFF;
  const unsigned short* gB3 = gB0 + (size_t)384 * DFF;
  floatx4 acc[4][8];
  const floatx4 z4 = {0.f, 0.f, 0.f, 0.f};
#pragma unroll
  for (int i = 0; i < 4; i++)
#pragma unroll
    for (int j = 0; j < 8; j++) acc[i][j] = z4;
  {
    unsigned short* d = smem + tid * 8;
    gld16(gA, d); gld16(gB0, d + 4096); gld16(gB1, d + 8192);
    gld16(gB2, d + 12288); gld16(gB3, d + 16384);
    unsigned short* e = smem + G_BUF + tid * 8;
    gld16(gA + 32, e); gld16(gB0 + 32, e + 4096); gld16(gB1 + 32, e + 8192);
    gld16(gB2 + 32, e + 12288); gld16(gB3 + 32, e + 16384);
  }
  asm volatile("s_waitcnt vmcnt(5)" ::: "memory");
  __builtin_amdgcn_s_barrier();
  int b = 0;
  for (int k = 0; k < 64; ++k) {
    const unsigned short* Bb = smem + b * G_BUF;
    int b2 = b + 2; if (b2 >= 3) b2 -= 3;
    unsigned short* db2 = smem + b2 * G_BUF + tid * 8;
    if (k < 62) {
      const int kt = (k + 2) * 32;
      gld16(gA + kt, db2); gld16(gB0 + kt, db2 + 4096); gld16(gB1 + kt, db2 + 8192);
      gld16(gB2 + kt, db2 + 12288); gld16(gB3 + kt, db2 + 16384);
    }
    __builtin_amdgcn_sched_barrier(0);
    bf16x8 a[4], bf[8];
#pragma unroll
    for (int mi = 0; mi < 4; mi++) a[mi] = *(const bf16x8*)(Bb + offA[mi]);
#pragma unroll
    for (int ni = 0; ni < 8; ni++) bf[ni] = *(const bf16x8*)(Bb + offB[ni]);
    __builtin_amdgcn_s_setprio(1);
#pragma unroll
    for (int mi = 0; mi < 4; mi++)
#pragma unroll
      for (int ni = 0; ni < 8; ni++)
        acc[mi][ni] = __builtin_amdgcn_mfma_f32_16x16x32_bf16(a[mi], bf[ni], acc[mi][ni], 0, 0, 0);
    __builtin_amdgcn_s_setprio(0);
    __builtin_amdgcn_sched_barrier(0);
    if (k < 62)       asm volatile("s_waitcnt vmcnt(5)" ::: "memory");
    else if (k == 62) asm volatile("s_waitcnt vmcnt(0)" ::: "memory");
    __builtin_amdgcn_s_barrier();
    b++; if (b == 3) b = 0;
  }
  const int rb = kq * 4;
#pragma unroll
  for (int mi = 0; mi < 4; mi++)
#pragma unroll
    for (int ni = 0; ni < 8; ni++)
#pragma unroll
      for (int r = 0; r < 4; r++)
        y[(size_t)(ent.z + wm + mi * 16 + rb + r) * DIM + n0 + wn + ni * 16 + fr] = acc[mi][ni][r];
}

// ---------------- GEMM2 atomic variant (fallback modes, unchanged) ----------------
__global__ __launch_bounds__(256) void gemm2_atomic_kernel(
    const unsigned short* __restrict__ h, const unsigned short* __restrict__ wdt,
    const int* __restrict__ idxR, const float* __restrict__ wslR,
    const int4* __restrict__ sched, float* __restrict__ out) {
  const int4 ent = sched[blockIdx.y];
  if (ent.x < 0) return;
  __shared__ unsigned short As[128 * 32];
  __shared__ unsigned short Bs[128 * 32];
  const int tid = threadIdx.x, lane = tid & 63, wid = tid >> 6;
  const int n0 = blockIdx.x * 128;
  const int wm = (wid >> 1) * 64, wn = (wid & 1) * 64;
  floatx4 acc[4][4];
  const floatx4 z4 = {0.f, 0.f, 0.f, 0.f};
#pragma unroll
  for (int i = 0; i < 4; i++)
#pragma unroll
    for (int j = 0; j < 4; j++) acc[i][j] = z4;
  const unsigned short* wdt_e = wdt + (size_t)ent.x * DFF * DIM;
  const int srow = tid >> 2, scol = (tid & 3) * 8;
  const unsigned short* ap0 = h + (size_t)(ent.z + srow) * DFF + scol;
  const unsigned short* ap1 = ap0 + (size_t)64 * DFF;
  const unsigned short* bp0 = wdt_e + (size_t)(n0 + srow) * DFF + scol;
  const unsigned short* bp1 = bp0 + (size_t)64 * DFF;
  unsigned short* as0 = As + tid * 8;
  unsigned short* as1 = As + (256 + tid) * 8;
  unsigned short* bs0 = Bs + tid * 8;
  unsigned short* bs1 = Bs + (256 + tid) * 8;
  const int fr = lane & 15, kq = (lane >> 4) * 8;
  for (int k0 = 0; k0 < DFF; k0 += 32) {
    __syncthreads();
    gld16(ap0 + k0, as0); gld16(ap1 + k0, as1);
    gld16(bp0 + k0, bs0); gld16(bp1 + k0, bs1);
    __syncthreads();
    bf16x8 af[4], bf[4];
#pragma unroll
    for (int mi = 0; mi < 4; mi++) af[mi] = *(const bf16x8*)(As + (wm + mi * 16 + fr) * 32 + kq);
#pragma unroll
    for (int ni = 0; ni < 4; ni++) bf[ni] = *(const bf16x8*)(Bs + (wn + ni * 16 + fr) * 32 + kq);
#pragma unroll
    for (int mi = 0; mi < 4; mi++)
#pragma unroll
      for (int ni = 0; ni < 4; ni++)
        acc[mi][ni] = __builtin_amdgcn_mfma_f32_16x16x32_bf16(af[mi], bf[ni], acc[mi][ni], 0, 0, 0);
  }
  const int rb0 = wm + (lane >> 4) * 4;
  const int cb0 = n0 + wn + fr;
#pragma unroll
  for (int mi = 0; mi < 4; mi++)
#pragma unroll
    for (int r = 0; r < 4; r++) {
      int lrow = rb0 + mi * 16 + r;
      if (ent.y < 0) {
        int tok = ent.z + lrow;
#pragma unroll
        for (int ni = 0; ni < 4; ni++)
          out[(size_t)tok * DIM + cb0 + ni * 16] = acc[mi][ni][r];
      } else {
        int tok = idxR[ent.y + lrow];
        float s = wslR[ent.y + lrow];
        if (s != 0.f) {
#pragma unroll
          for (int ni = 0; ni < 4; ni++)
            atomicAdd(&out[(size_t)tok * DIM + cb0 + ni * 16], s * acc[mi][ni][r]);
        }
      }
    }
}

// ---------------- combine: out[t] = y[t] + w1*y[p1] + w2*y[p2] ----------------
__global__ __launch_bounds__(256) void combine_kernel(const float* __restrict__ y,
                                                      const int4* __restrict__ tokE,
                                                      const float2* __restrict__ tokW,
                                                      const int* __restrict__ pref,
                                                      float* __restrict__ out) {
  const int t = blockIdx.x;
  const int c = threadIdx.x * 4;
  int4 te = tokE[t];
  float2 tw = tokW[t];
  int p1 = 4096 + pref[te.x] * 128 + te.y;
  int p2 = 4096 + pref[te.z] * 128 + te.w;
  float4 a = *(const float4*)(y + (size_t)t * DIM + c);
  float4 b = *(const float4*)(y + (size_t)p1 * DIM + c);
  float4 d = *(const float4*)(y + (size_t)p2 * DIM + c);
  float4 o;
  o.x = a.x + tw.x * b.x + tw.y * d.x;
  o.y = a.y + tw.x * b.y + tw.y * d.y;
  o.z = a.z + tw.x * b.z + tw.y * d.z;
  o.w = a.w + tw.x * b.w + tw.y * d.w;
  *(float4*)(out + (size_t)t * DIM + c) = o;
}

extern "C" void kernel_launch(void* const* d_in, const int* in_sizes, int n_in,
                              void* d_out, int out_size, void* d_ws, size_t ws_size,
                              hipStream_t stream) {
  const float* x  = (const float*)d_in[0];
  const float* rw = (const float*)d_in[1];
  const float* rb = (const float*)d_in[2];
  const float* wg = (const float*)d_in[3];
  const float* wu = (const float*)d_in[4];
  const float* wd = (const float*)d_in[5];
  float* out = (float*)d_out;

  // mode A2: unified, atomic-free (y aliases dead wgt/wut); needs ~163.28 MB (ws known >= 163.32 MB)
  // mode B : sequential e0 + routed, atomic gemm2; needs ~146.7 MB
  // mode C : per-expert loop, atomic gemm2
  const bool modeA = ws_size >= (size_t)163300000;
  const bool modeB = !modeA && ws_size >= (size_t)146700000;
  const size_t H_ROWS = modeA ? 13184 : (modeB ? 9088 : 4096);
  const int rsb = modeA ? 4096 : 0;

  char* p = (char*)d_ws;
  unsigned short* xb  = (unsigned short*)p; p += (size_t)T_TOK * DIM * 2;       // 8,388,608
  unsigned short* h   = (unsigned short*)p; p += H_ROWS * DFF * 2;
  unsigned short* wgt = (unsigned short*)p;                                     // y aliases wgt+wut in mode A
  float*          y   = (float*)p;          p += (size_t)NE * DIM * DFF * 2;
  unsigned short* wut = (unsigned short*)p; p += (size_t)NE * DIM * DFF * 2;
  unsigned short* wdt = (unsigned short*)p; p += (size_t)NE * DIM * DFF * 2;
  int*   idxR = (int*)p;   p += (size_t)NR * 4096 * 4;                          // 114,688
  float* wslR;
  if (modeA) { wslR = (float*)wdt; }                                            // scratch: overwritten by transpose later
  else       { wslR = (float*)p; p += (size_t)NR * 4096 * 4; }
  int*   cnt  = (int*)p;      p += 64;
  int*   pref = (int*)p;      p += 64;
  int4*  schedAll = (int4*)p; p += 2048;
  int4*  schedP   = (int4*)p; p += 4096;
  int4*  tokE = (int4*)p;     p += (size_t)T_TOK * 16;
  float2* tokW = (float2*)p;  p += (size_t)T_TOK * 8;

  cvt_x_kernel<<<dim3(T_TOK * DIM / 4 / 256), 256, 0, stream>>>((const float4*)x, (ushort4*)xb);
  hipMemsetAsync(cnt, 0, 64, stream);
  router_kernel<<<dim3(T_TOK / 4), 256, 0, stream>>>(x, rw, rb, idxR, wslR, cnt, tokE, tokW);
  sched_kernel<<<dim3(1), 256, 0, stream>>>(cnt, idxR, wslR, schedAll, schedP, pref, rsb);
  transpose_cvt_kernel<<<dim3(32, 32, 24), 256, 0, stream>>>(wg, wu, wd, wgt, wut, wdt);

  if (modeA) {
    gemm1_kernel<<<dim3((DFF / 256) * NY), 512, 0, stream>>>(xb, wgt, wut, idxR, schedAll, h, NY);
    gemm2_kernel<<<dim3((DIM / 512) * NY), 512, 0, stream>>>(h, wdt, schedAll, y, NY);
    combine_kernel<<<dim3(T_TOK), 256, 0, stream>>>(y, tokE, tokW, pref, out);
  } else if (modeB) {
    gemm1_kernel<<<dim3((DFF / 256) * 32), 512, 0, stream>>>(xb, wgt, wut, idxR, schedAll, h, 32);
    gemm2_atomic_kernel<<<dim3(DIM / 128, 32), 256, 0, stream>>>(h, wdt, idxR, wslR, schedAll, out);
    gemm1_kernel<<<dim3((DFF / 256) * MAXNB), 512, 0, stream>>>(xb, wgt, wut, idxR, schedAll + 32, h, MAXNB);
    gemm2_atomic_kernel<<<dim3(DIM / 128, MAXNB), 256, 0, stream>>>(h, wdt, idxR, wslR, schedAll + 32, out);
  } else {
    gemm1_kernel<<<dim3((DFF / 256) * 32), 512, 0, stream>>>(xb, wgt, wut, idxR, schedAll, h, 32);
    gemm2_atomic_kernel<<<dim3(DIM / 128, 32), 256, 0, stream>>>(h, wdt, idxR, wslR, schedAll, out);
    for (int e = 0; e < NR; e++) {
      gemm1_kernel<<<dim3((DFF / 256) * 32), 512, 0, stream>>>(xb, wgt, wut, idxR, schedP + e * 32, h, 32);
      gemm2_atomic_kernel<<<dim3(DIM / 128, 32), 256, 0, stream>>>(h, wdt, idxR, wslR, schedP + e * 32, out);
    }
  }
}